// Round 18
// baseline (195.843 us; speedup 1.0000x reference)
//
#include <hip/hip_runtime.h>
#include <hip/hip_bf16.h>

typedef __attribute__((ext_vector_type(8))) __bf16 bf16x8;
typedef __attribute__((ext_vector_type(4))) __bf16 bf16x4;
typedef __attribute__((ext_vector_type(4))) float f32x4;

constexpr int B = 4, S = 2048, D = 1024, H = 16, DK = 64;

#define GLOAD16(gp, lp)                                                              \
  __builtin_amdgcn_global_load_lds((const __attribute__((address_space(1))) void*)(gp), \
                                   (__attribute__((address_space(3))) void*)(lp), 16, 0, 0)

// ---------------------------------------------------------------------------
// Kernel 0: one-shot f32 -> bf16 conversion of X, w_qkv, w_o into workspace.
// ---------------------------------------------------------------------------
__global__ __launch_bounds__(256) void convert_bf16(const float* __restrict__ X,
                                                    const float* __restrict__ Wqkv,
                                                    const float* __restrict__ Wo,
                                                    __bf16* __restrict__ Xb,
                                                    __bf16* __restrict__ Wqkvb,
                                                    __bf16* __restrict__ Wob) {
  const int NX = B * S * D;
  const int NW = 3 * D * D;
  const int NO = D * D;
  const int total8 = (NX + NW + NO) / 8;
  for (int i = blockIdx.x * blockDim.x + threadIdx.x; i < total8;
       i += gridDim.x * blockDim.x) {
    const int e = i * 8;
    const float* src;
    __bf16* dst;
    int off;
    if (e < NX) {
      src = X; dst = Xb; off = e;
    } else if (e < NX + NW) {
      src = Wqkv; dst = Wqkvb; off = e - NX;
    } else {
      src = Wo; dst = Wob; off = e - NX - NW;
    }
    float4 a = *reinterpret_cast<const float4*>(src + off);
    float4 b = *reinterpret_cast<const float4*>(src + off + 4);
    bf16x8 v = {(__bf16)a.x, (__bf16)a.y, (__bf16)a.z, (__bf16)a.w,
                (__bf16)b.x, (__bf16)b.y, (__bf16)b.z, (__bf16)b.w};
    *reinterpret_cast<bf16x8*>(dst + off) = v;
  }
}

// ---------------------------------------------------------------------------
// Kernel 1 (round 14, unchanged): qkv GEMM, 2-phase double-buffered LDS.
// ---------------------------------------------------------------------------
__global__ __launch_bounds__(256) void qkv_gemm(const __bf16* __restrict__ Xb,
                                                const __bf16* __restrict__ Wb,
                                                const float* __restrict__ bias,
                                                __bf16* __restrict__ Qb,
                                                __bf16* __restrict__ Kb,
                                                __bf16* __restrict__ VTb) {
  __shared__ __bf16 As[2][128 * 64];
  __shared__ __bf16 Bs[2][128 * 64];
  const int tid = threadIdx.x;
  const int lane = tid & 63;
  const int w = tid >> 6;
  const int wr = w >> 1, wc = w & 1;
  const int lr = lane & 15, lb = lane >> 4;
  const int m0 = blockIdx.x * 128, n0 = blockIdx.y * 128;

  int srow[4], sgcol[4];
#pragma unroll
  for (int rnd = 0; rnd < 4; ++rnd) {
    const int i = rnd * 256 + tid;
    srow[rnd] = i >> 3;
    sgcol[rnd] = ((i & 7) ^ (srow[rnd] & 7)) << 3;
  }

  f32x4 acc[4][4];
#pragma unroll
  for (int i = 0; i < 4; ++i)
#pragma unroll
    for (int j = 0; j < 4; ++j) acc[i][j] = f32x4{0.f, 0.f, 0.f, 0.f};

#pragma unroll
  for (int rnd = 0; rnd < 4; ++rnd) {
    GLOAD16(&Xb[(size_t)(m0 + srow[rnd]) * D + sgcol[rnd]],
            (char*)&As[0][0] + rnd * 4096 + w * 1024);
    GLOAD16(&Wb[(size_t)(n0 + srow[rnd]) * D + sgcol[rnd]],
            (char*)&Bs[0][0] + rnd * 4096 + w * 1024);
  }
  __syncthreads();

  int cur = 0;
  for (int k0 = 0; k0 < D; k0 += 64) {
    if (k0 + 64 < D) {
#pragma unroll
      for (int rnd = 0; rnd < 4; ++rnd) {
        GLOAD16(&Xb[(size_t)(m0 + srow[rnd]) * D + k0 + 64 + sgcol[rnd]],
                (char*)&As[cur ^ 1][0] + rnd * 4096 + w * 1024);
        GLOAD16(&Wb[(size_t)(n0 + srow[rnd]) * D + k0 + 64 + sgcol[rnd]],
                (char*)&Bs[cur ^ 1][0] + rnd * 4096 + w * 1024);
      }
    }

    bf16x8 af[4][2], bfr[4][2];
#pragma unroll
    for (int m = 0; m < 4; ++m) {
      const int row = wr * 64 + m * 16 + lr;
#pragma unroll
      for (int ks = 0; ks < 2; ++ks)
        af[m][ks] = *reinterpret_cast<const bf16x8*>(
            (const char*)&As[cur][0] + row * 128 + (((ks * 32 + lb * 8) << 1) ^ ((row & 7) << 4)));
    }
#pragma unroll
    for (int n = 0; n < 4; ++n) {
      const int row = wc * 64 + n * 16 + lr;
#pragma unroll
      for (int ks = 0; ks < 2; ++ks)
        bfr[n][ks] = *reinterpret_cast<const bf16x8*>(
            (const char*)&Bs[cur][0] + row * 128 + (((ks * 32 + lb * 8) << 1) ^ ((row & 7) << 4)));
    }
#pragma unroll
    for (int m = 0; m < 4; ++m)
#pragma unroll
      for (int n = 0; n < 4; ++n) {
        acc[m][n] = __builtin_amdgcn_mfma_f32_16x16x32_bf16(af[m][0], bfr[n][0], acc[m][n], 0, 0, 0);
        acc[m][n] = __builtin_amdgcn_mfma_f32_16x16x32_bf16(af[m][1], bfr[n][1], acc[m][n], 0, 0, 0);
      }
    __syncthreads();
    cur ^= 1;
  }

  const int seg = n0 >> 10;
  if (seg == 2) {
#pragma unroll
    for (int m = 0; m < 4; ++m) {
      const int tb = m0 + wr * 64 + m * 16 + lb * 4;
      const int bb2 = tb >> 11;
      const int s = tb & 2047;
#pragma unroll
      for (int n = 0; n < 4; ++n) {
        const int c = n0 + wc * 64 + n * 16 + lr;
        const int cc = c & 1023;
        const int h = cc >> 6, dk = cc & 63;
        const float bv = bias[c];
        bf16x4 pv;
#pragma unroll
        for (int r = 0; r < 4; ++r) pv[r] = (__bf16)(acc[m][n][r] + bv);
        *reinterpret_cast<bf16x4*>(
            &VTb[(((size_t)bb2 * H + h) * DK + dk) * S + s]) = pv;
      }
    }
  } else {
#pragma unroll
    for (int m = 0; m < 4; ++m)
#pragma unroll
      for (int n = 0; n < 4; ++n) {
        const int c = n0 + wc * 64 + n * 16 + lr;
        const int cc = c & 1023;
        const int h = cc >> 6, dk = cc & 63;
        const float bv = bias[c];
#pragma unroll
        for (int r = 0; r < 4; ++r) {
          const int t = m0 + wr * 64 + m * 16 + lb * 4 + r;
          const int bb2 = t >> 11;
          const int s = t & 2047;
          const float v = acc[m][n][r] + bv;
          const size_t bh = (size_t)bb2 * H + h;
          if (seg == 0)
            Qb[(bh * S + s) * DK + dk] = (__bf16)(v * 0.180336893f);  // 0.125*log2(e)
          else
            Kb[(bh * S + s) * DK + dk] = (__bf16)v;
        }
      }
  }
}

// ---------------------------------------------------------------------------
// Kernel 2 (round 17): FUSED-PAIR causal flash attention.
// Block owns q-tiles qtA=pr and qtB=pr+8 (same head) and sweeps kv ONCE
// (nt = 2*qtB+2 tiles): while A is active (t < ntwA) the SAME staged K/V
// tile and the SAME kf/vf register fragments feed both q-tiles' MFMAs --
// cutting LDS reads/staging/barriers ~26% vs two separate passes (attn is
// LDS-throughput-bound: ~45-50us of per-CU LDS-pipe time measured r16).
// Complementary makespans: blocks flat & flat+256 (same CU, round-robin)
// get pr=p and 7-p -> per-CU tile totals sum to 50, uniform.
// 8 waves x 16 q-rows per q-tile; KVBLK=64; K/V LDS double-buffer (1 barrier
// per tile); two Ps regions (one lgkm wait); per-ks PV loop bounds VGPR.
// Swapped QK^T; exp2 softmax; defer-max THR=11; MFMA row-sum denominator.
// ---------------------------------------------------------------------------
__global__ __launch_bounds__(512, 4) void attn_fwd(const __bf16* __restrict__ Qb,
                                                   const __bf16* __restrict__ Kb,
                                                   const __bf16* __restrict__ VTb,
                                                   __bf16* __restrict__ AO) {
  __shared__ __bf16 Kl[2][64 * 64];
  __shared__ __bf16 Vl[2][64 * 64];
  __shared__ __bf16 PsA[8][16][72];
  __shared__ __bf16 PsB[8][16][72];
  const int tid = threadIdx.x;
  const int lane = tid & 63;
  const int w = tid >> 6;  // 0..7
  const int lr = lane & 15, lb = lane >> 4;

  const int flat = blockIdx.x;
  const int xcd = flat & 7;
  const int hg = (flat >> 3) & 7;
  const int s = flat >> 6;                 // 0..7
  const int pr = (s < 4) ? s : (11 - s);   // slots s and s+4 -> pr p and 7-p
  const int bh = hg * 8 + xcd;
  const int bb = bh >> 4, h = bh & 15;

  const int qtA = pr, qtB = pr + 8;
  const __bf16* Q = Qb + (size_t)bh * S * DK;
  const __bf16* K = Kb + (size_t)bh * S * DK;
  const __bf16* VT = VTb + (size_t)bh * DK * S;

  const int q0A = qtA * 128 + w * 16;
  const int q0B = qtB * 128 + w * 16;
  const int ntwA = 2 * qtA + 1 + (w >> 2);
  const int ntwB = 2 * qtB + 1 + (w >> 2);
  const int nt = 2 * qtB + 2;

  // staging: 512 threads cover one 64x64 bf16 tile (8KB) per instruction
  const int srow = tid >> 3;
  const int sc8 = (tid & 7) * 8;
  const int sbyte = srow * 128 + sc8 * 2;
  const int sswz = (srow & 7) << 4;
  const int rsw = (lr & 7) << 4;

  bf16x8 ones;
#pragma unroll
  for (int i = 0; i < 8; ++i) ones[i] = (__bf16)1.0f;

  bf16x8 qfA[2], qfB[2];
#pragma unroll
  for (int d = 0; d < 2; ++d) {
    qfA[d] = *reinterpret_cast<const bf16x8*>(&Q[(size_t)(q0A + lr) * DK + d * 32 + lb * 8]);
    qfB[d] = *reinterpret_cast<const bf16x8*>(&Q[(size_t)(q0B + lr) * DK + d * 32 + lb * 8]);
  }

  // prologue: stage tile 0 into buffer 0
  {
    bf16x8 k0 = *reinterpret_cast<const bf16x8*>(K + (size_t)srow * DK + sc8);
    bf16x8 v0 = *reinterpret_cast<const bf16x8*>(VT + (size_t)srow * S + sc8);
    *reinterpret_cast<bf16x8*>((char*)&Kl[0][0] + (sbyte ^ sswz)) = k0;
    *reinterpret_cast<bf16x8*>((char*)&Vl[0][0] + (sbyte ^ sswz)) = v0;
  }
  __syncthreads();

  f32x4 oA[4], oB[4], lsA, lsB;
#pragma unroll
  for (int n = 0; n < 4; ++n) {
    oA[n] = f32x4{0.f, 0.f, 0.f, 0.f};
    oB[n] = f32x4{0.f, 0.f, 0.f, 0.f};
  }
  lsA = f32x4{0.f, 0.f, 0.f, 0.f};
  lsB = f32x4{0.f, 0.f, 0.f, 0.f};
  float mA = -1e30f, mB = -1e30f;  // per q = lr, exp2 domain

  int cur = 0;
  for (int t = 0; t < nt; ++t) {
    const int kv0 = t * 64;
    const bool have_next = (t + 1 < nt);
    bf16x8 gk0, gv0;
    if (have_next) {  // issue next-tile loads early; latency hides under compute
      gk0 = *reinterpret_cast<const bf16x8*>(K + ((size_t)(kv0 + 64) + srow) * DK + sc8);
      gv0 = *reinterpret_cast<const bf16x8*>(VT + (size_t)srow * S + (kv0 + 64) + sc8);
    }

    const bool actA = (t < ntwA);  // wave-uniform
    const bool actB = (t < ntwB);

    if (actB) {  // (actB implies nothing about actA; actA implies actB)
      const char* kbase = (const char*)&Kl[cur][0];
      bf16x8 kf[4][2];
#pragma unroll
      for (int kc = 0; kc < 4; ++kc) {
        const int row = kc * 16 + lr;
#pragma unroll
        for (int d = 0; d < 2; ++d)
          kf[kc][d] = *reinterpret_cast<const bf16x8*>(
              kbase + row * 128 + ((d * 64 + lb * 16) ^ rsw));
      }

      // ---- q-tile B ----
      {
        f32x4 st[4];
        __builtin_amdgcn_s_setprio(1);
#pragma unroll
        for (int kc = 0; kc < 4; ++kc) {
          f32x4 z = f32x4{0.f, 0.f, 0.f, 0.f};
          z = __builtin_amdgcn_mfma_f32_16x16x32_bf16(kf[kc][0], qfB[0], z, 0, 0, 0);
          z = __builtin_amdgcn_mfma_f32_16x16x32_bf16(kf[kc][1], qfB[1], z, 0, 0, 0);
          st[kc] = z;
        }
        __builtin_amdgcn_s_setprio(0);
        if (t == ntwB - 1) {
          const int qg = q0B + lr;
#pragma unroll
          for (int kc = 0; kc < 4; ++kc)
#pragma unroll
            for (int r = 0; r < 4; ++r) {
              const int kg = kv0 + kc * 16 + 4 * lb + r;
              if (kg > qg) st[kc][r] = -1e30f;
            }
        }
        float a0 = fmaxf(fmaxf(st[0][0], st[0][1]), fmaxf(st[0][2], st[0][3]));
        float a1 = fmaxf(fmaxf(st[1][0], st[1][1]), fmaxf(st[1][2], st[1][3]));
        float a2 = fmaxf(fmaxf(st[2][0], st[2][1]), fmaxf(st[2][2], st[2][3]));
        float a3 = fmaxf(fmaxf(st[3][0], st[3][1]), fmaxf(st[3][2], st[3][3]));
        float mx = fmaxf(fmaxf(a0, a1), fmaxf(a2, a3));
        mx = fmaxf(mx, __shfl_xor(mx, 16, 64));
        mx = fmaxf(mx, __shfl_xor(mx, 32, 64));
        if (__any(mx > mB + 11.f)) {
          const float nm = fmaxf(mB, mx);
          const float alpha = exp2f(mB - nm);
          mB = nm;
#pragma unroll
          for (int r = 0; r < 4; ++r) {
            const float ao = __shfl(alpha, 4 * lb + r, 64);
#pragma unroll
            for (int n = 0; n < 4; ++n) oB[n][r] *= ao;
            lsB[r] *= ao;
          }
        }
#pragma unroll
        for (int kc = 0; kc < 4; ++kc) {
          bf16x4 pk;
#pragma unroll
          for (int r = 0; r < 4; ++r) pk[r] = (__bf16)exp2f(st[kc][r] - mB);
          *reinterpret_cast<bf16x4*>(&PsB[w][lr][kc * 16 + 4 * lb]) = pk;
        }
      }

      // ---- q-tile A (shares kf) ----
      if (actA) {
        f32x4 st[4];
        __builtin_amdgcn_s_setprio(1);
#pragma unroll
        for (int kc = 0; kc < 4; ++kc) {
          f32x4 z = f32x4{0.f, 0.f, 0.f, 0.f};
          z = __builtin_amdgcn_mfma_f32_16x16x32_bf16(kf[kc][0], qfA[0], z, 0, 0, 0);
          z = __builtin_amdgcn_mfma_f32_16x16x32_bf16(kf[kc][1], qfA[1], z, 0, 0, 0);
          st[kc] = z;
        }
        __builtin_amdgcn_s_setprio(0);
        if (t == ntwA - 1) {
          const int qg = q0A + lr;
#pragma unroll
          for (int kc = 0; kc < 4; ++kc)
#pragma unroll
            for (int r = 0; r < 4; ++r) {
              const int kg = kv0 + kc * 16 + 4 * lb + r;
              if (kg > qg) st[kc][r] = -1e30f;
            }
        }
        float a0 = fmaxf(fmaxf(st[0][0], st[0][1]), fmaxf(st[0][2], st[0][3]));
        float a1 = fmaxf(fmaxf(st[1][0], st[1][1]), fmaxf(st[1][2], st[1][3]));
        float a2 = fmaxf(fmaxf(st[2][0], st[2][1]), fmaxf(st[2][2], st[2][3]));
        float a3 = fmaxf(fmaxf(st[3][0], st[3][1]), fmaxf(st[3][2], st[3][3]));
        float mx = fmaxf(fmaxf(a0, a1), fmaxf(a2, a3));
        mx = fmaxf(mx, __shfl_xor(mx, 16, 64));
        mx = fmaxf(mx, __shfl_xor(mx, 32, 64));
        if (__any(mx > mA + 11.f)) {
          const float nm = fmaxf(mA, mx);
          const float alpha = exp2f(mA - nm);
          mA = nm;
#pragma unroll
          for (int r = 0; r < 4; ++r) {
            const float ao = __shfl(alpha, 4 * lb + r, 64);
#pragma unroll
            for (int n = 0; n < 4; ++n) oA[n][r] *= ao;
            lsA[r] *= ao;
          }
        }
#pragma unroll
        for (int kc = 0; kc < 4; ++kc) {
          bf16x4 pk;
#pragma unroll
          for (int r = 0; r < 4; ++r) pk[r] = (__bf16)exp2f(st[kc][r] - mA);
          *reinterpret_cast<bf16x4*>(&PsA[w][lr][kc * 16 + 4 * lb]) = pk;
        }
      }

      asm volatile("s_waitcnt lgkmcnt(0)" ::: "memory");
      __builtin_amdgcn_sched_barrier(0);

      // PV for both q-tiles, sharing vf reads; per-ks to bound registers
      const char* vbase = (const char*)&Vl[cur][0];
      __builtin_amdgcn_s_setprio(1);
#pragma unroll
      for (int ks = 0; ks < 2; ++ks) {
        bf16x8 vf[4];
#pragma unroll
        for (int n = 0; n < 4; ++n) {
          const int row = n * 16 + lr;
          vf[n] = *reinterpret_cast<const bf16x8*>(
              vbase + row * 128 + ((ks * 64 + lb * 16) ^ rsw));
        }
        bf16x8 paB = *reinterpret_cast<const bf16x8*>(&PsB[w][lr][ks * 32 + lb * 8]);
#pragma unroll
        for (int n = 0; n < 4; ++n)
          oB[n] = __builtin_amdgcn_mfma_f32_16x16x32_bf16(paB, vf[n], oB[n], 0, 0, 0);
        lsB = __builtin_amdgcn_mfma_f32_16x16x32_bf16(paB, ones, lsB, 0, 0, 0);
        if (actA) {
          bf16x8 paA = *reinterpret_cast<const bf16x8*>(&PsA[w][lr][ks * 32 + lb * 8]);
#pragma unroll
          for (int n = 0; n < 4; ++n)
            oA[n] = __builtin_amdgcn_mfma_f32_16x16x32_bf16(paA, vf[n], oA[n], 0, 0, 0);
          lsA = __builtin_amdgcn_mfma_f32_16x16x32_bf16(paA, ones, lsA, 0, 0, 0);
        }
      }
      __builtin_amdgcn_s_setprio(0);
    }

    // stage tile t+1 into the other buffer, one barrier, flip
    if (have_next) {
      *reinterpret_cast<bf16x8*>((char*)&Kl[cur ^ 1][0] + (sbyte ^ sswz)) = gk0;
      *reinterpret_cast<bf16x8*>((char*)&Vl[cur ^ 1][0] + (sbyte ^ sswz)) = gv0;
    }
    __syncthreads();
    cur ^= 1;
  }

  // epilogues: o and lsum share the C layout (q = q0 + 4lb + r) -> no shuffle
#pragma unroll
  for (int r = 0; r < 4; ++r) {
    const float invA = 1.f / lsA[r];
    const int qA = q0A + 4 * lb + r;
#pragma unroll
    for (int n = 0; n < 4; ++n)
      AO[((size_t)(bb * S + qA)) * D + h * DK + n * 16 + lr] = (__bf16)(oA[n][r] * invA);
  }
#pragma unroll
  for (int r = 0; r < 4; ++r) {
    const float invB = 1.f / lsB[r];
    const int qB = q0B + 4 * lb + r;
#pragma unroll
    for (int n = 0; n < 4; ++n)
      AO[((size_t)(bb * S + qB)) * D + h * DK + n * 16 + lr] = (__bf16)(oB[n][r] * invB);
  }
}

// ---------------------------------------------------------------------------
// Kernel 3 (round 14, unchanged): out = AO @ Wob^T, 2-phase dbuf, f32 out.
// ---------------------------------------------------------------------------
__global__ __launch_bounds__(256) void out_gemm(const __bf16* __restrict__ AOp,
                                                const __bf16* __restrict__ Wb,
                                                float* __restrict__ Out) {
  __shared__ __bf16 As[2][128 * 64];
  __shared__ __bf16 Bs[2][128 * 64];
  const int tid = threadIdx.x;
  const int lane = tid & 63;
  const int w = tid >> 6;
  const int wr = w >> 1, wc = w & 1;
  const int lr = lane & 15, lb = lane >> 4;
  const int m0 = blockIdx.x * 128, n0 = blockIdx.y * 128;

  int srow[4], sgcol[4];
#pragma unroll
  for (int rnd = 0; rnd < 4; ++rnd) {
    const int i = rnd * 256 + tid;
    srow[rnd] = i >> 3;
    sgcol[rnd] = ((i & 7) ^ (srow[rnd] & 7)) << 3;
  }

  f32x4 acc[4][4];
#pragma unroll
  for (int i = 0; i < 4; ++i)
#pragma unroll
    for (int j = 0; j < 4; ++j) acc[i][j] = f32x4{0.f, 0.f, 0.f, 0.f};

#pragma unroll
  for (int rnd = 0; rnd < 4; ++rnd) {
    GLOAD16(&AOp[(size_t)(m0 + srow[rnd]) * D + sgcol[rnd]],
            (char*)&As[0][0] + rnd * 4096 + w * 1024);
    GLOAD16(&Wb[(size_t)(n0 + srow[rnd]) * D + sgcol[rnd]],
            (char*)&Bs[0][0] + rnd * 4096 + w * 1024);
  }
  __syncthreads();

  int cur = 0;
  for (int k0 = 0; k0 < D; k0 += 64) {
    if (k0 + 64 < D) {
#pragma unroll
      for (int rnd = 0; rnd < 4; ++rnd) {
        GLOAD16(&AOp[(size_t)(m0 + srow[rnd]) * D + k0 + 64 + sgcol[rnd]],
                (char*)&As[cur ^ 1][0] + rnd * 4096 + w * 1024);
        GLOAD16(&Wb[(size_t)(n0 + srow[rnd]) * D + k0 + 64 + sgcol[rnd]],
                (char*)&Bs[cur ^ 1][0] + rnd * 4096 + w * 1024);
      }
    }

    bf16x8 af[4][2], bfr[4][2];
#pragma unroll
    for (int m = 0; m < 4; ++m) {
      const int row = wr * 64 + m * 16 + lr;
#pragma unroll
      for (int ks = 0; ks < 2; ++ks)
        af[m][ks] = *reinterpret_cast<const bf16x8*>(
            (const char*)&As[cur][0] + row * 128 + (((ks * 32 + lb * 8) << 1) ^ ((row & 7) << 4)));
    }
#pragma unroll
    for (int n = 0; n < 4; ++n) {
      const int row = wc * 64 + n * 16 + lr;
#pragma unroll
      for (int ks = 0; ks < 2; ++ks)
        bfr[n][ks] = *reinterpret_cast<const bf16x8*>(
            (const char*)&Bs[cur][0] + row * 128 + (((ks * 32 + lb * 8) << 1) ^ ((row & 7) << 4)));
    }
#pragma unroll
    for (int m = 0; m < 4; ++m)
#pragma unroll
      for (int n = 0; n < 4; ++n) {
        acc[m][n] = __builtin_amdgcn_mfma_f32_16x16x32_bf16(af[m][0], bfr[n][0], acc[m][n], 0, 0, 0);
        acc[m][n] = __builtin_amdgcn_mfma_f32_16x16x32_bf16(af[m][1], bfr[n][1], acc[m][n], 0, 0, 0);
      }
    __syncthreads();
    cur ^= 1;
  }

#pragma unroll
  for (int m = 0; m < 4; ++m)
#pragma unroll
    for (int n = 0; n < 4; ++n)
#pragma unroll
      for (int r = 0; r < 4; ++r)
        Out[(size_t)(m0 + wr * 64 + m * 16 + lb * 4 + r) * D + n0 + wc * 64 + n * 16 + lr] =
            acc[m][n][r];
}

// ---------------------------------------------------------------------------
extern "C" void kernel_launch(void* const* d_in, const int* in_sizes, int n_in,
                              void* d_out, int out_size, void* d_ws, size_t ws_size,
                              hipStream_t stream) {
  (void)in_sizes; (void)n_in; (void)out_size; (void)ws_size;
  const float* x = (const float*)d_in[0];
  // d_in[1] = causal mask — recomputed analytically, not read
  const float* w_qkv = (const float*)d_in[2];
  const float* b_qkv = (const float*)d_in[3];
  const float* w_o = (const float*)d_in[4];
  float* out = (float*)d_out;

  const size_t qkv_elems = (size_t)B * H * S * DK;  // 8,388,608 (= B*S*D)
  __bf16* Qb = (__bf16*)d_ws;
  __bf16* Kb = Qb + qkv_elems;
  __bf16* VTb = Kb + qkv_elems;
  __bf16* AO = VTb + qkv_elems;
  __bf16* Xb = AO + qkv_elems;
  __bf16* Wqkvb = Xb + (size_t)B * S * D;
  __bf16* Wob = Wqkvb + (size_t)3 * D * D;  // total ~92 MB of workspace

  convert_bf16<<<2048, 256, 0, stream>>>(x, w_qkv, w_o, Xb, Wqkvb, Wob);
  qkv_gemm<<<dim3(64, 24), 256, 0, stream>>>(Xb, Wqkvb, b_qkv, Qb, Kb, VTb);
  attn_fwd<<<dim3(8 * (B * H)), 512, 0, stream>>>(Qb, Kb, VTb, AO);
  out_gemm<<<dim3(64, 8), 256, 0, stream>>>(AO, Wob, out);
}

// Round 19
// 166.029 us; speedup vs baseline: 1.1796x; 1.1796x over previous
//
#include <hip/hip_runtime.h>
#include <hip/hip_bf16.h>

typedef __attribute__((ext_vector_type(8))) __bf16 bf16x8;
typedef __attribute__((ext_vector_type(4))) __bf16 bf16x4;
typedef __attribute__((ext_vector_type(4))) float f32x4;

constexpr int B = 4, S = 2048, D = 1024, H = 16, DK = 64;

#define GLOAD16(gp, lp)                                                              \
  __builtin_amdgcn_global_load_lds((const __attribute__((address_space(1))) void*)(gp), \
                                   (__attribute__((address_space(3))) void*)(lp), 16, 0, 0)

// ---------------------------------------------------------------------------
// Kernel 0: one-shot f32 -> bf16 conversion of X, w_qkv, w_o into workspace.
// ---------------------------------------------------------------------------
__global__ __launch_bounds__(256) void convert_bf16(const float* __restrict__ X,
                                                    const float* __restrict__ Wqkv,
                                                    const float* __restrict__ Wo,
                                                    __bf16* __restrict__ Xb,
                                                    __bf16* __restrict__ Wqkvb,
                                                    __bf16* __restrict__ Wob) {
  const int NX = B * S * D;
  const int NW = 3 * D * D;
  const int NO = D * D;
  const int total8 = (NX + NW + NO) / 8;
  for (int i = blockIdx.x * blockDim.x + threadIdx.x; i < total8;
       i += gridDim.x * blockDim.x) {
    const int e = i * 8;
    const float* src;
    __bf16* dst;
    int off;
    if (e < NX) {
      src = X; dst = Xb; off = e;
    } else if (e < NX + NW) {
      src = Wqkv; dst = Wqkvb; off = e - NX;
    } else {
      src = Wo; dst = Wob; off = e - NX - NW;
    }
    float4 a = *reinterpret_cast<const float4*>(src + off);
    float4 b = *reinterpret_cast<const float4*>(src + off + 4);
    bf16x8 v = {(__bf16)a.x, (__bf16)a.y, (__bf16)a.z, (__bf16)a.w,
                (__bf16)b.x, (__bf16)b.y, (__bf16)b.z, (__bf16)b.w};
    *reinterpret_cast<bf16x8*>(dst + off) = v;
  }
}

// ---------------------------------------------------------------------------
// Kernel 1 (round 14, unchanged): qkv GEMM, 2-phase double-buffered LDS.
// ---------------------------------------------------------------------------
__global__ __launch_bounds__(256) void qkv_gemm(const __bf16* __restrict__ Xb,
                                                const __bf16* __restrict__ Wb,
                                                const float* __restrict__ bias,
                                                __bf16* __restrict__ Qb,
                                                __bf16* __restrict__ Kb,
                                                __bf16* __restrict__ VTb) {
  __shared__ __bf16 As[2][128 * 64];
  __shared__ __bf16 Bs[2][128 * 64];
  const int tid = threadIdx.x;
  const int lane = tid & 63;
  const int w = tid >> 6;
  const int wr = w >> 1, wc = w & 1;
  const int lr = lane & 15, lb = lane >> 4;
  const int m0 = blockIdx.x * 128, n0 = blockIdx.y * 128;

  int srow[4], sgcol[4];
#pragma unroll
  for (int rnd = 0; rnd < 4; ++rnd) {
    const int i = rnd * 256 + tid;
    srow[rnd] = i >> 3;
    sgcol[rnd] = ((i & 7) ^ (srow[rnd] & 7)) << 3;
  }

  f32x4 acc[4][4];
#pragma unroll
  for (int i = 0; i < 4; ++i)
#pragma unroll
    for (int j = 0; j < 4; ++j) acc[i][j] = f32x4{0.f, 0.f, 0.f, 0.f};

#pragma unroll
  for (int rnd = 0; rnd < 4; ++rnd) {
    GLOAD16(&Xb[(size_t)(m0 + srow[rnd]) * D + sgcol[rnd]],
            (char*)&As[0][0] + rnd * 4096 + w * 1024);
    GLOAD16(&Wb[(size_t)(n0 + srow[rnd]) * D + sgcol[rnd]],
            (char*)&Bs[0][0] + rnd * 4096 + w * 1024);
  }
  __syncthreads();

  int cur = 0;
  for (int k0 = 0; k0 < D; k0 += 64) {
    if (k0 + 64 < D) {
#pragma unroll
      for (int rnd = 0; rnd < 4; ++rnd) {
        GLOAD16(&Xb[(size_t)(m0 + srow[rnd]) * D + k0 + 64 + sgcol[rnd]],
                (char*)&As[cur ^ 1][0] + rnd * 4096 + w * 1024);
        GLOAD16(&Wb[(size_t)(n0 + srow[rnd]) * D + k0 + 64 + sgcol[rnd]],
                (char*)&Bs[cur ^ 1][0] + rnd * 4096 + w * 1024);
      }
    }

    bf16x8 af[4][2], bfr[4][2];
#pragma unroll
    for (int m = 0; m < 4; ++m) {
      const int row = wr * 64 + m * 16 + lr;
#pragma unroll
      for (int ks = 0; ks < 2; ++ks)
        af[m][ks] = *reinterpret_cast<const bf16x8*>(
            (const char*)&As[cur][0] + row * 128 + (((ks * 32 + lb * 8) << 1) ^ ((row & 7) << 4)));
    }
#pragma unroll
    for (int n = 0; n < 4; ++n) {
      const int row = wc * 64 + n * 16 + lr;
#pragma unroll
      for (int ks = 0; ks < 2; ++ks)
        bfr[n][ks] = *reinterpret_cast<const bf16x8*>(
            (const char*)&Bs[cur][0] + row * 128 + (((ks * 32 + lb * 8) << 1) ^ ((row & 7) << 4)));
    }
#pragma unroll
    for (int m = 0; m < 4; ++m)
#pragma unroll
      for (int n = 0; n < 4; ++n) {
        acc[m][n] = __builtin_amdgcn_mfma_f32_16x16x32_bf16(af[m][0], bfr[n][0], acc[m][n], 0, 0, 0);
        acc[m][n] = __builtin_amdgcn_mfma_f32_16x16x32_bf16(af[m][1], bfr[n][1], acc[m][n], 0, 0, 0);
      }
    __syncthreads();
    cur ^= 1;
  }

  const int seg = n0 >> 10;
  if (seg == 2) {
#pragma unroll
    for (int m = 0; m < 4; ++m) {
      const int tb = m0 + wr * 64 + m * 16 + lb * 4;
      const int bb2 = tb >> 11;
      const int s = tb & 2047;
#pragma unroll
      for (int n = 0; n < 4; ++n) {
        const int c = n0 + wc * 64 + n * 16 + lr;
        const int cc = c & 1023;
        const int h = cc >> 6, dk = cc & 63;
        const float bv = bias[c];
        bf16x4 pv;
#pragma unroll
        for (int r = 0; r < 4; ++r) pv[r] = (__bf16)(acc[m][n][r] + bv);
        *reinterpret_cast<bf16x4*>(
            &VTb[(((size_t)bb2 * H + h) * DK + dk) * S + s]) = pv;
      }
    }
  } else {
#pragma unroll
    for (int m = 0; m < 4; ++m)
#pragma unroll
      for (int n = 0; n < 4; ++n) {
        const int c = n0 + wc * 64 + n * 16 + lr;
        const int cc = c & 1023;
        const int h = cc >> 6, dk = cc & 63;
        const float bv = bias[c];
#pragma unroll
        for (int r = 0; r < 4; ++r) {
          const int t = m0 + wr * 64 + m * 16 + lb * 4 + r;
          const int bb2 = t >> 11;
          const int s = t & 2047;
          const float v = acc[m][n][r] + bv;
          const size_t bh = (size_t)bb2 * H + h;
          if (seg == 0)
            Qb[(bh * S + s) * DK + dk] = (__bf16)(v * 0.180336893f);  // 0.125*log2(e)
          else
            Kb[(bh * S + s) * DK + dk] = (__bf16)v;
        }
      }
  }
}

// ---------------------------------------------------------------------------
// Kernel 2 (round 18 = round 16 + global_load_lds staging).
// 8 waves x 16 q-rows, KVBLK=64, paired q-tiles (pr,15-pr) -> uniform
// 34-tile makespan; grid 512 (bh=hg*8+xcd pins head K/V to one XCD L2).
// K/V LDS double-buffer; staging now via global_load_lds w16: linear dest +
// inverse-swizzled global source col + swizzled reads (rule 21; same
// convention as the GEMMs). One barrier per tile (its vmcnt(0) drain covers
// the DMA, same wait point the reg-staged path had; saves the global->reg->
// ds_write round trip on the saturated LDS pipe).
// Swapped QK^T; exp2 softmax; defer-max THR=11; MFMA row-sum denominator.
// ---------------------------------------------------------------------------
__global__ __launch_bounds__(512, 4) void attn_fwd(const __bf16* __restrict__ Qb,
                                                   const __bf16* __restrict__ Kb,
                                                   const __bf16* __restrict__ VTb,
                                                   __bf16* __restrict__ AO) {
  __shared__ __bf16 Kl[2][64 * 64];
  __shared__ __bf16 Vl[2][64 * 64];
  __shared__ __bf16 Ps[8][16][72];
  const int tid = threadIdx.x;
  const int lane = tid & 63;
  const int w = tid >> 6;  // 0..7
  const int lr = lane & 15, lb = lane >> 4;

  const int flat = blockIdx.x;
  const int xcd = flat & 7;
  const int idx = flat >> 3;
  const int hg = idx & 7;
  const int pr = idx >> 3;  // 0..7 -> pair (pr, 15-pr)
  const int bh = hg * 8 + xcd;
  const int bb = bh >> 4, h = bh & 15;

  const __bf16* Q = Qb + (size_t)bh * S * DK;
  const __bf16* K = Kb + (size_t)bh * S * DK;
  const __bf16* VT = VTb + (size_t)bh * DK * S;

  // staging: 512 threads cover one 64x64 bf16 tile per gload_lds instr.
  // linear LDS dest; global source col pre-swizzled (rule 21).
  const int srow = tid >> 3;                        // 0..63
  const int sgcol = ((tid & 7) ^ (srow & 7)) << 3;  // pre-swizzled source col
  const int ldst = srow * 128 + (tid & 7) * 16;     // linear LDS byte offset
  const int rsw = (lr & 7) << 4;

  bf16x8 ones;
#pragma unroll
  for (int i = 0; i < 8; ++i) ones[i] = (__bf16)1.0f;

  for (int pass = 0; pass < 2; ++pass) {
    const int qt = pass ? (15 - pr) : pr;
    const int q0w = qt * 128 + w * 16;      // this wave's 16 q-rows
    const int nt = 2 * qt + 2;              // block trip count
    const int ntw = 2 * qt + 1 + (w >> 2);  // this wave's compute trips

    bf16x8 qf[2];
#pragma unroll
    for (int d = 0; d < 2; ++d)
      qf[d] = *reinterpret_cast<const bf16x8*>(
          &Q[(size_t)(q0w + lr) * DK + d * 32 + lb * 8]);

    // prologue: stage tile 0 into buffer 0 (prev pass's reads ended at its
    // final barrier; that barrier also drained any in-flight DMA)
    GLOAD16(K + (size_t)srow * DK + sgcol, (char*)&Kl[0][0] + ldst);
    GLOAD16(VT + (size_t)srow * S + sgcol, (char*)&Vl[0][0] + ldst);
    __syncthreads();  // compiler drains vmcnt before s_barrier

    f32x4 o[4], lsum;
#pragma unroll
    for (int n = 0; n < 4; ++n) o[n] = f32x4{0.f, 0.f, 0.f, 0.f};
    lsum = f32x4{0.f, 0.f, 0.f, 0.f};
    float mrun = -1e30f;  // per q = lr, exp2 domain

    int cur = 0;
    for (int t = 0; t < nt; ++t) {
      const int kv0 = t * 64;
      const bool have_next = (t + 1 < nt);
      if (have_next) {  // DMA next tile into the other buffer; overlaps compute
        GLOAD16(K + ((size_t)(kv0 + 64) + srow) * DK + sgcol,
                (char*)&Kl[cur ^ 1][0] + ldst);
        GLOAD16(VT + (size_t)srow * S + (kv0 + 64) + sgcol,
                (char*)&Vl[cur ^ 1][0] + ldst);
      }

      if (t < ntw) {
        const char* kbase = (const char*)&Kl[cur][0];
        const char* vbase = (const char*)&Vl[cur][0];
        bf16x8 kf[4][2];
#pragma unroll
        for (int kc = 0; kc < 4; ++kc) {
          const int row = kc * 16 + lr;
#pragma unroll
          for (int d = 0; d < 2; ++d)
            kf[kc][d] = *reinterpret_cast<const bf16x8*>(
                kbase + row * 128 + ((d * 64 + lb * 16) ^ rsw));
        }

        // swapped QK^T: st[kc][r] = S^T[k=kv0+kc*16+4lb+r][q=q0w+lr]
        f32x4 st[4];
        __builtin_amdgcn_s_setprio(1);
#pragma unroll
        for (int kc = 0; kc < 4; ++kc) {
          f32x4 z = f32x4{0.f, 0.f, 0.f, 0.f};
          z = __builtin_amdgcn_mfma_f32_16x16x32_bf16(kf[kc][0], qf[0], z, 0, 0, 0);
          z = __builtin_amdgcn_mfma_f32_16x16x32_bf16(kf[kc][1], qf[1], z, 0, 0, 0);
          st[kc] = z;
        }
        __builtin_amdgcn_s_setprio(0);

        if (t == ntw - 1) {  // diagonal tile: mask k > q (per-lane)
          const int qg = q0w + lr;
#pragma unroll
          for (int kc = 0; kc < 4; ++kc)
#pragma unroll
            for (int r = 0; r < 4; ++r) {
              const int kg = kv0 + kc * 16 + 4 * lb + r;
              if (kg > qg) st[kc][r] = -1e30f;
            }
        }

        // column max over 64 k: nested-triple in-lane tree + 2 shuffles
        float a0 = fmaxf(fmaxf(st[0][0], st[0][1]), fmaxf(st[0][2], st[0][3]));
        float a1 = fmaxf(fmaxf(st[1][0], st[1][1]), fmaxf(st[1][2], st[1][3]));
        float a2 = fmaxf(fmaxf(st[2][0], st[2][1]), fmaxf(st[2][2], st[2][3]));
        float a3 = fmaxf(fmaxf(st[3][0], st[3][1]), fmaxf(st[3][2], st[3][3]));
        float mx = fmaxf(fmaxf(a0, a1), fmaxf(a2, a3));
        mx = fmaxf(mx, __shfl_xor(mx, 16, 64));
        mx = fmaxf(mx, __shfl_xor(mx, 32, 64));

        if (__any(mx > mrun + 11.f)) {  // defer-max (exp2 domain)
          const float nm = fmaxf(mrun, mx);
          const float alpha = exp2f(mrun - nm);
          mrun = nm;
#pragma unroll
          for (int r = 0; r < 4; ++r) {
            const float ao = __shfl(alpha, 4 * lb + r, 64);
#pragma unroll
            for (int n = 0; n < 4; ++n) o[n][r] *= ao;
            lsum[r] *= ao;
          }
        }

        // P = exp2(st - mrun) -> bf16, packed b64 into wave-private LDS
#pragma unroll
        for (int kc = 0; kc < 4; ++kc) {
          bf16x4 pk;
#pragma unroll
          for (int r = 0; r < 4; ++r) pk[r] = (__bf16)exp2f(st[kc][r] - mrun);
          *reinterpret_cast<bf16x4*>(&Ps[w][lr][kc * 16 + 4 * lb]) = pk;
        }

        asm volatile("s_waitcnt lgkmcnt(0)" ::: "memory");
        __builtin_amdgcn_sched_barrier(0);

        bf16x8 pa[2];
#pragma unroll
        for (int ks = 0; ks < 2; ++ks)
          pa[ks] = *reinterpret_cast<const bf16x8*>(&Ps[w][lr][ks * 32 + lb * 8]);
        bf16x8 vf[4][2];
#pragma unroll
        for (int n = 0; n < 4; ++n) {
          const int row = n * 16 + lr;
#pragma unroll
          for (int ks = 0; ks < 2; ++ks)
            vf[n][ks] = *reinterpret_cast<const bf16x8*>(
                vbase + row * 128 + ((ks * 64 + lb * 16) ^ rsw));
        }

        __builtin_amdgcn_s_setprio(1);
#pragma unroll
        for (int n = 0; n < 4; ++n) {
          o[n] = __builtin_amdgcn_mfma_f32_16x16x32_bf16(pa[0], vf[n][0], o[n], 0, 0, 0);
          o[n] = __builtin_amdgcn_mfma_f32_16x16x32_bf16(pa[1], vf[n][1], o[n], 0, 0, 0);
        }
        // denominator: P row-sums via all-ones B fragment (C layout, q=4lb+r)
        lsum = __builtin_amdgcn_mfma_f32_16x16x32_bf16(pa[0], ones, lsum, 0, 0, 0);
        lsum = __builtin_amdgcn_mfma_f32_16x16x32_bf16(pa[1], ones, lsum, 0, 0, 0);
        __builtin_amdgcn_s_setprio(0);
      }

      __syncthreads();  // drains vmcnt(0): next buffer staged; buf[cur] free
      cur ^= 1;
    }

    // epilogue: o and lsum share the C layout (q = q0w + 4lb + r) -> no shuffle
#pragma unroll
    for (int r = 0; r < 4; ++r) {
      const float inv = 1.f / lsum[r];
      const int q = q0w + 4 * lb + r;
#pragma unroll
      for (int n = 0; n < 4; ++n)
        AO[((size_t)(bb * S + q)) * D + h * DK + n * 16 + lr] = (__bf16)(o[n][r] * inv);
    }
  }
}

// ---------------------------------------------------------------------------
// Kernel 3 (round 14, unchanged): out = AO @ Wob^T, 2-phase dbuf, f32 out.
// ---------------------------------------------------------------------------
__global__ __launch_bounds__(256) void out_gemm(const __bf16* __restrict__ AOp,
                                                const __bf16* __restrict__ Wb,
                                                float* __restrict__ Out) {
  __shared__ __bf16 As[2][128 * 64];
  __shared__ __bf16 Bs[2][128 * 64];
  const int tid = threadIdx.x;
  const int lane = tid & 63;
  const int w = tid >> 6;
  const int wr = w >> 1, wc = w & 1;
  const int lr = lane & 15, lb = lane >> 4;
  const int m0 = blockIdx.x * 128, n0 = blockIdx.y * 128;

  int srow[4], sgcol[4];
#pragma unroll
  for (int rnd = 0; rnd < 4; ++rnd) {
    const int i = rnd * 256 + tid;
    srow[rnd] = i >> 3;
    sgcol[rnd] = ((i & 7) ^ (srow[rnd] & 7)) << 3;
  }

  f32x4 acc[4][4];
#pragma unroll
  for (int i = 0; i < 4; ++i)
#pragma unroll
    for (int j = 0; j < 4; ++j) acc[i][j] = f32x4{0.f, 0.f, 0.f, 0.f};

#pragma unroll
  for (int rnd = 0; rnd < 4; ++rnd) {
    GLOAD16(&AOp[(size_t)(m0 + srow[rnd]) * D + sgcol[rnd]],
            (char*)&As[0][0] + rnd * 4096 + w * 1024);
    GLOAD16(&Wb[(size_t)(n0 + srow[rnd]) * D + sgcol[rnd]],
            (char*)&Bs[0][0] + rnd * 4096 + w * 1024);
  }
  __syncthreads();

  int cur = 0;
  for (int k0 = 0; k0 < D; k0 += 64) {
    if (k0 + 64 < D) {
#pragma unroll
      for (int rnd = 0; rnd < 4; ++rnd) {
        GLOAD16(&AOp[(size_t)(m0 + srow[rnd]) * D + k0 + 64 + sgcol[rnd]],
                (char*)&As[cur ^ 1][0] + rnd * 4096 + w * 1024);
        GLOAD16(&Wb[(size_t)(n0 + srow[rnd]) * D + k0 + 64 + sgcol[rnd]],
                (char*)&Bs[cur ^ 1][0] + rnd * 4096 + w * 1024);
      }
    }

    bf16x8 af[4][2], bfr[4][2];
#pragma unroll
    for (int m = 0; m < 4; ++m) {
      const int row = wr * 64 + m * 16 + lr;
#pragma unroll
      for (int ks = 0; ks < 2; ++ks)
        af[m][ks] = *reinterpret_cast<const bf16x8*>(
            (const char*)&As[cur][0] + row * 128 + (((ks * 32 + lb * 8) << 1) ^ ((row & 7) << 4)));
    }
#pragma unroll
    for (int n = 0; n < 4; ++n) {
      const int row = wc * 64 + n * 16 + lr;
#pragma unroll
      for (int ks = 0; ks < 2; ++ks)
        bfr[n][ks] = *reinterpret_cast<const bf16x8*>(
            (const char*)&Bs[cur][0] + row * 128 + (((ks * 32 + lb * 8) << 1) ^ ((row & 7) << 4)));
    }
#pragma unroll
    for (int m = 0; m < 4; ++m)
#pragma unroll
      for (int n = 0; n < 4; ++n) {
        acc[m][n] = __builtin_amdgcn_mfma_f32_16x16x32_bf16(af[m][0], bfr[n][0], acc[m][n], 0, 0, 0);
        acc[m][n] = __builtin_amdgcn_mfma_f32_16x16x32_bf16(af[m][1], bfr[n][1], acc[m][n], 0, 0, 0);
      }
    __syncthreads();
    cur ^= 1;
  }

#pragma unroll
  for (int m = 0; m < 4; ++m)
#pragma unroll
    for (int n = 0; n < 4; ++n)
#pragma unroll
      for (int r = 0; r < 4; ++r)
        Out[(size_t)(m0 + wr * 64 + m * 16 + lb * 4 + r) * D + n0 + wc * 64 + n * 16 + lr] =
            acc[m][n][r];
}

// ---------------------------------------------------------------------------
extern "C" void kernel_launch(void* const* d_in, const int* in_sizes, int n_in,
                              void* d_out, int out_size, void* d_ws, size_t ws_size,
                              hipStream_t stream) {
  (void)in_sizes; (void)n_in; (void)out_size; (void)ws_size;
  const float* x = (const float*)d_in[0];
  // d_in[1] = causal mask — recomputed analytically, not read
  const float* w_qkv = (const float*)d_in[2];
  const float* b_qkv = (const float*)d_in[3];
  const float* w_o = (const float*)d_in[4];
  float* out = (float*)d_out;

  const size_t qkv_elems = (size_t)B * H * S * DK;  // 8,388,608 (= B*S*D)
  __bf16* Qb = (__bf16*)d_ws;
  __bf16* Kb = Qb + qkv_elems;
  __bf16* VTb = Kb + qkv_elems;
  __bf16* AO = VTb + qkv_elems;
  __bf16* Xb = AO + qkv_elems;
  __bf16* Wqkvb = Xb + (size_t)B * S * D;
  __bf16* Wob = Wqkvb + (size_t)3 * D * D;  // total ~92 MB of workspace

  convert_bf16<<<2048, 256, 0, stream>>>(x, w_qkv, w_o, Xb, Wqkvb, Wob);
  qkv_gemm<<<dim3(64, 24), 256, 0, stream>>>(Xb, Wqkvb, b_qkv, Qb, Kb, VTb);
  attn_fwd<<<dim3(8 * (B * H)), 512, 0, stream>>>(Qb, Kb, VTb, AO);
  out_gemm<<<dim3(64, 8), 256, 0, stream>>>(AO, Wob, out);
}